// Round 12
// baseline (331.711 us; speedup 1.0000x reference)
//
#include <hip/hip_runtime.h>
#include <hip/hip_bf16.h>

typedef unsigned short u16;
typedef __attribute__((ext_vector_type(8))) short short8;
typedef __attribute__((ext_vector_type(4))) short s4;
typedef __attribute__((ext_vector_type(4))) float floatx4;

__device__ __forceinline__ float lrelu(float x) { return x > 0.f ? x : 0.01f * x; }

__device__ __forceinline__ short bf16bits(float v) {
  __hip_bfloat16 t = __float2bfloat16(v);
  return *reinterpret_cast<short*>(&t);
}
__device__ __forceinline__ float bits2f(u16 b) {
  __hip_bfloat16 t = *reinterpret_cast<__hip_bfloat16*>(&b);
  return __bfloat162float(t);
}
__device__ __forceinline__ short8 pack8(floatx4 x0, floatx4 x1) {
  short8 b;
#pragma unroll
  for (int r = 0; r < 4; ++r) { b[r] = bf16bits(x0[r]); b[4 + r] = bf16bits(x1[r]); }
  return b;
}

// ---------------------------------------------------------------------------
// prep_all: ONE launch for all data prep that depends on perm.
//   blocks [0, 768): fragment-pack the six weights (z = bid>>7, 128 blocks ea)
//   blocks [768, 768+6258): gather X rows into sorted order + fragment-pack
// Pack layout: W[K][N] f32 -> P[(g*NS+s)*512 + lane*8 + j] bf16,
// g = col-group (16 cols), s = k-step (32 k), lane = quad*16+m16:
//   P[...] = W[s*32 + quad*8 + j][g*16 + m16]
// Wave af fragment load = 64 lanes x 16B CONTIGUOUS (8 cache lines).
// Xp granule (16 rows): Xp[(tg*4+s)*512 + lane*8 + j] =
//   bf16(X[perm[tg*16+m16]][s*32+quad*8+j]); pad rows (>= n) write zeros.
// (r9 lesson: the gather must stay a standalone full-TLP stream.)
// ---------------------------------------------------------------------------
__global__ __launch_bounds__(256) void prep_all(
    const float* __restrict__ W1, const float* __restrict__ W2,
    const float* __restrict__ W3, const float* __restrict__ W4,
    const float* __restrict__ W5, const float* __restrict__ W6,
    u16* __restrict__ P1, u16* __restrict__ P2, u16* __restrict__ P3,
    u16* __restrict__ P4, u16* __restrict__ P5, u16* __restrict__ P6,
    const float* __restrict__ X, const int* __restrict__ perm,
    u16* __restrict__ Xp, int n) {
  const int bid = blockIdx.x;
  if (bid < 768) {
    const float* W; u16* P; int N, ls, total;
    switch (bid >> 7) {
      case 0: W = W1; P = P1; N = 512; ls = 2; total = 8192;  break;  // K=128
      case 1: W = W2; P = P2; N = 512; ls = 4; total = 32768; break;  // K=512
      case 2: W = W3; P = P3; N = 256; ls = 4; total = 16384; break;  // K=512
      case 3: W = W4; P = P4; N = 512; ls = 3; total = 16384; break;  // K=256
      case 4: W = W5; P = P5; N = 512; ls = 4; total = 32768; break;  // K=512
      default: W = W6; P = P6; N = 256; ls = 4; total = 16384; break; // K=512
    }
    const int t = (bid & 127) * 256 + threadIdx.x;
    if (t >= total) return;
    const int lane = t & 63;
    const int sg   = t >> 6;
    const int m16  = lane & 15;
    const int quad = lane >> 4;
    const int s    = sg & ((1 << ls) - 1);
    const int g    = sg >> ls;
    const int nn   = g * 16 + m16;
    const int k0   = s * 32 + quad * 8;
    short8 out;
#pragma unroll
    for (int j = 0; j < 8; ++j) out[j] = bf16bits(W[(size_t)(k0 + j) * N + nn]);
    *(short8*)(P + (size_t)t * 8) = out;
  } else {
    const int t = (bid - 768) * 256 + threadIdx.x;   // (tg*4 + s)*64 + lane
    const int lane = t & 63;
    const int s    = (t >> 6) & 3;
    const int tg   = t >> 8;
    const int m16  = lane & 15;
    const int quad = lane >> 4;
    const int R    = tg * 16 + m16;
    short8 out = {0, 0, 0, 0, 0, 0, 0, 0};
    if (R < n) {
      const int src = perm[R];
      const float* xp = X + (size_t)src * 128 + s * 32 + quad * 8;
      out = pack8(*(const floatx4*)xp, *(const floatx4*)(xp + 4));
    }
    *(short8*)(Xp + (size_t)t * 8) = out;
  }
}

// ---------------------------------------------------------------------------
// Counting sort of node ids by dag id (2000 bins).
// ---------------------------------------------------------------------------
__global__ __launch_bounds__(256) void hist_kernel(const int* __restrict__ dag,
                                                   int* __restrict__ hist, int n) {
  int i = blockIdx.x * blockDim.x + threadIdx.x;
  if (i < n) atomicAdd(&hist[dag[i]], 1);
}

__global__ __launch_bounds__(256) void scan_offsets(const int* __restrict__ hist,
                                                    int* __restrict__ cursor) {
  __shared__ int part[256];
  const int t = threadIdx.x;
  const int base = t * 8;
  int loc[8];
  int s = 0;
#pragma unroll
  for (int j = 0; j < 8; ++j) {
    int v = (base + j < 2000) ? hist[base + j] : 0;
    loc[j] = s;
    s += v;
  }
  part[t] = s;
  __syncthreads();
  int val = s;
  for (int off = 1; off < 256; off <<= 1) {
    int tmp = (t >= off) ? part[t - off] : 0;
    __syncthreads();
    val += tmp;
    part[t] = val;
    __syncthreads();
  }
  const int chunkBase = (t == 0) ? 0 : part[t - 1];
#pragma unroll
  for (int j = 0; j < 8; ++j)
    if (base + j < 2000) cursor[base + j] = chunkBase + loc[j];
}

// scatter + dsort tail fill in one launch (tail threads write -1 pad).
__global__ __launch_bounds__(256) void scatter_kernel(const int* __restrict__ dag,
                                                      int* __restrict__ cursor,
                                                      int* __restrict__ perm,
                                                      int* __restrict__ dsort,
                                                      int n, int nTot) {
  int i = blockIdx.x * blockDim.x + threadIdx.x;
  if (i < n) {
    int d = dag[i];
    int p = atomicAdd(&cursor[d], 1);
    perm[p] = i;
    dsort[p] = d;
  } else if (i < nTot) {
    dsort[i] = -1;
  }
}

// ---------------------------------------------------------------------------
// Fused node stack, r12 = r11 dual-prefetch body at 3 blocks/CU:
// launch_bounds(512,3) (cap 85; r11 measured the dual-pf body at VGPR=76,
// so it fits) + grid 768. Combines the two independently-measured wins:
//   r8: 3 blocks/CU, no dual-pf       -> 170 us
//   r11: 2 blocks/CU, dual-pf, VGPR76 -> 155 us
// Occupancy covers barrier/epilogue phases; dual-pf covers per-step operand
// latency. FALSIFIER: VGPR 84-85 AND FETCH > 50MB => spilled => r11 config.
//   L1: H1 = lrelu(Xp@W1+b1)  K=128   af+bx packed-global (16B/lane coalesced)
//   L2: H2 = lrelu(H1@W2+b2)  K=512   bx LDS + af global, BOTH prefetched
//   L3: G  = lrelu(H2@W3+b3)  K=512   same; -> LDS, dag-sum -> atomics s1
// mfma(af, bx, acc): out row = bx-row (mi*16+m16), col = af-row (ni*16+quad*4+r).
// ---------------------------------------------------------------------------
#define NODE_ROWS 48
#define NODE_NP 520
#define NODE_P3 264
#define NODE_LDS (NODE_ROWS * NODE_NP * 2 + 16)   // 49936 B -> 3 blocks/CU

__global__ __launch_bounds__(512, 3) void node_fused(
    const u16* __restrict__ Xp, const u16* __restrict__ W1p,
    const u16* __restrict__ W2p, const u16* __restrict__ W3p,
    const float* __restrict__ b1, const float* __restrict__ b2,
    const float* __restrict__ b3, float* __restrict__ s1,
    const int* __restrict__ dsort, int* __restrict__ tilectr, int nTiles) {
  extern __shared__ __align__(16) char lds[];
  u16* H = (u16*)lds;   // [48][520] for H1/H2, reused as [48][264] for L3
  int* tileSlot = (int*)(lds + NODE_ROWS * NODE_NP * 2);

  const int tid  = threadIdx.x;
  const int wv   = tid >> 6;
  const int lane = tid & 63;
  const int m16  = lane & 15;
  const int quad = lane >> 4;

  // loop-invariant fragment base pointers (chunk = 512 u16 per (g,s))
  const u16* wp1 = W1p + (size_t)(wv * 4) * 2048 + lane * 8;   // g-stride 4*512
  const u16* wp2 = W2p + (size_t)(wv * 4) * 8192 + lane * 8;   // g-stride 16*512
  const u16* wp3 = W3p + (size_t)(wv * 2) * 8192 + lane * 8;

  for (;;) {
    if (tid == 0) *tileSlot = atomicAdd(tilectr, 1);
    __syncthreads();                      // also: all waves done with prev walk
    const int tile = *tileSlot;
    if (tile >= nTiles) return;           // uniform exit

    // ---- layer 1: K=128, N=512; bx from packed global Xp (4 steps, no pf)
    {
      const u16* xpp = Xp + (size_t)tile * 12 * 512 + lane * 8;
      floatx4 acc[4][3];
#pragma unroll
      for (int i = 0; i < 4; ++i)
#pragma unroll
        for (int j = 0; j < 3; ++j) { floatx4 z = {0.f, 0.f, 0.f, 0.f}; acc[i][j] = z; }
#pragma unroll
      for (int s = 0; s < 4; ++s) {
        short8 af[4], bx[3];
#pragma unroll
        for (int ni = 0; ni < 4; ++ni) af[ni] = *(const short8*)(wp1 + ni * 2048 + s * 512);
#pragma unroll
        for (int mi = 0; mi < 3; ++mi) bx[mi] = *(const short8*)(xpp + (mi * 4 + s) * 512);
#pragma unroll
        for (int ni = 0; ni < 4; ++ni)
#pragma unroll
          for (int mi = 0; mi < 3; ++mi)
            acc[ni][mi] = __builtin_amdgcn_mfma_f32_16x16x32_bf16(af[ni], bx[mi], acc[ni][mi], 0, 0, 0);
      }
      const int n0 = wv * 64;
#pragma unroll
      for (int ni = 0; ni < 4; ++ni) {
        const int nb = n0 + ni * 16 + quad * 4;
        floatx4 bb = *(const floatx4*)&b1[nb];
#pragma unroll
        for (int mi = 0; mi < 3; ++mi) {
          s4 h;
#pragma unroll
          for (int r = 0; r < 4; ++r) h[r] = bf16bits(lrelu(acc[ni][mi][r] + bb[r]));
          *(s4*)&H[(size_t)(mi * 16 + m16) * NODE_NP + nb] = h;
        }
      }
    }
    __syncthreads();

    // ---- layer 2: K=512, N=512; DUAL prefetch (af global + bx LDS)
    {
      const u16* hp = H + (size_t)m16 * NODE_NP + quad * 8;
      floatx4 acc[4][3];
#pragma unroll
      for (int i = 0; i < 4; ++i)
#pragma unroll
        for (int j = 0; j < 3; ++j) { floatx4 z = {0.f, 0.f, 0.f, 0.f}; acc[i][j] = z; }
      short8 af[4], bx[3];
#pragma unroll
      for (int ni = 0; ni < 4; ++ni) af[ni] = *(const short8*)(wp2 + ni * 8192);
#pragma unroll
      for (int mi = 0; mi < 3; ++mi) bx[mi] = *(const short8*)(hp + mi * (16 * NODE_NP));
#pragma unroll 2
      for (int s = 0; s < 16; ++s) {
        const int sn = (s + 1) & 15;   // s=15 wraps: dead reload, branchless
        short8 afn[4], bxn[3];
#pragma unroll
        for (int ni = 0; ni < 4; ++ni) afn[ni] = *(const short8*)(wp2 + ni * 8192 + sn * 512);
#pragma unroll
        for (int mi = 0; mi < 3; ++mi)
          bxn[mi] = *(const short8*)(hp + mi * (16 * NODE_NP) + sn * 32);
#pragma unroll
        for (int ni = 0; ni < 4; ++ni)
#pragma unroll
          for (int mi = 0; mi < 3; ++mi)
            acc[ni][mi] = __builtin_amdgcn_mfma_f32_16x16x32_bf16(af[ni], bx[mi], acc[ni][mi], 0, 0, 0);
#pragma unroll
        for (int ni = 0; ni < 4; ++ni) af[ni] = afn[ni];
#pragma unroll
        for (int mi = 0; mi < 3; ++mi) bx[mi] = bxn[mi];
      }
      __syncthreads();   // all waves done reading H1 before overwriting
      const int n0 = wv * 64;
#pragma unroll
      for (int ni = 0; ni < 4; ++ni) {
        const int nb = n0 + ni * 16 + quad * 4;
        floatx4 bb = *(const floatx4*)&b2[nb];
#pragma unroll
        for (int mi = 0; mi < 3; ++mi) {
          s4 h;
#pragma unroll
          for (int r = 0; r < 4; ++r) h[r] = bf16bits(lrelu(acc[ni][mi][r] + bb[r]));
          *(s4*)&H[(size_t)(mi * 16 + m16) * NODE_NP + nb] = h;
        }
      }
    }
    __syncthreads();

    // ---- layer 3: K=512, N=256; DUAL prefetch; wave cols [wv*32, wv*32+32)
    {
      const u16* hp = H + (size_t)m16 * NODE_NP + quad * 8;
      floatx4 acc[2][3];
#pragma unroll
      for (int i = 0; i < 2; ++i)
#pragma unroll
        for (int j = 0; j < 3; ++j) { floatx4 z = {0.f, 0.f, 0.f, 0.f}; acc[i][j] = z; }
      short8 af[2], bx[3];
#pragma unroll
      for (int ni = 0; ni < 2; ++ni) af[ni] = *(const short8*)(wp3 + ni * 8192);
#pragma unroll
      for (int mi = 0; mi < 3; ++mi) bx[mi] = *(const short8*)(hp + mi * (16 * NODE_NP));
#pragma unroll 2
      for (int s = 0; s < 16; ++s) {
        const int sn = (s + 1) & 15;
        short8 afn[2], bxn[3];
#pragma unroll
        for (int ni = 0; ni < 2; ++ni) afn[ni] = *(const short8*)(wp3 + ni * 8192 + sn * 512);
#pragma unroll
        for (int mi = 0; mi < 3; ++mi)
          bxn[mi] = *(const short8*)(hp + mi * (16 * NODE_NP) + sn * 32);
#pragma unroll
        for (int ni = 0; ni < 2; ++ni)
#pragma unroll
          for (int mi = 0; mi < 3; ++mi)
            acc[ni][mi] = __builtin_amdgcn_mfma_f32_16x16x32_bf16(af[ni], bx[mi], acc[ni][mi], 0, 0, 0);
#pragma unroll
        for (int ni = 0; ni < 2; ++ni) af[ni] = afn[ni];
#pragma unroll
        for (int mi = 0; mi < 3; ++mi) bx[mi] = bxn[mi];
      }
      __syncthreads();   // all waves done reading H2
      const int n0 = wv * 32;
#pragma unroll
      for (int ni = 0; ni < 2; ++ni) {
        const int nb = n0 + ni * 16 + quad * 4;
        floatx4 bb = *(const floatx4*)&b3[nb];
#pragma unroll
        for (int mi = 0; mi < 3; ++mi) {
          s4 h;
#pragma unroll
          for (int r = 0; r < 4; ++r) h[r] = bf16bits(lrelu(acc[ni][mi][r] + bb[r]));
          *(s4*)&H[(size_t)(mi * 16 + m16) * NODE_P3 + nb] = h;
        }
      }
    }
    __syncthreads();

    // ---- segmented dag walk: wave wv owns rows [(wv>>2)*24, +24), cols
    // [(wv&3)*64, +64); lane = local col. dsort sorted; -1 (pad) skipped.
    {
      const int rh = (wv >> 2) * 24;
      const int c0 = (wv & 3) * 64;
      const int myDag = dsort[(size_t)tile * NODE_ROWS + rh + (lane & 31)];
      float* so = s1 + c0 + lane;
      float run = 0.f;
      int cur = __shfl(myDag, 0);
#pragma unroll
      for (int rb = 0; rb < 24; rb += 8) {
        float v[8];
#pragma unroll
        for (int j = 0; j < 8; ++j)
          v[j] = bits2f(H[(size_t)(rh + rb + j) * NODE_P3 + c0 + lane]);
#pragma unroll
        for (int j = 0; j < 8; ++j) {
          int d = __shfl(myDag, rb + j);              // wave-uniform
          if (d != cur) {
            if (cur >= 0) atomicAdd(so + (size_t)cur * 256, run);
            run = 0.f; cur = d;
          }
          run += v[j];
        }
      }
      if (cur >= 0) atomicAdd(so + (size_t)cur * 256, run);
    }
  }
}

// ---------------------------------------------------------------------------
// Global stack, node-style, 16-row tiles: 125 blocks (2000 = 125x16).
//   L4: H = lrelu(s1@W4+b4)  K=256  bx packed on the fly from f32 s1
//   L5: H = lrelu(H@W5+b5)   K=512  bx LDS, af packed-global prefetched
//   L6: g3 = lrelu(H@W6+b6)  K=512  mask-weighted row-reduce -> atomics s2
// ---------------------------------------------------------------------------
#define G_ROWS 16
#define G_LDS (G_ROWS * NODE_NP * 2)   // 16640 B

__global__ __launch_bounds__(512, 3) void fused3g(
    const float* __restrict__ A0, const u16* __restrict__ W4p,
    const u16* __restrict__ W5p, const u16* __restrict__ W6p,
    const float* __restrict__ b4, const float* __restrict__ b5,
    const float* __restrict__ b6, const float* __restrict__ mask,
    float* __restrict__ out, int s2Off, int M) {
  extern __shared__ __align__(16) char lds[];
  u16* H = (u16*)lds;   // [16][520]

  const int tid  = threadIdx.x;
  const int wv   = tid >> 6;
  const int lane = tid & 63;
  const int m16  = lane & 15;
  const int quad = lane >> 4;
  const int row0 = blockIdx.x * G_ROWS;

  const u16* wp4 = W4p + (size_t)(wv * 4) * 4096 + lane * 8;   // NS=8
  const u16* wp5 = W5p + (size_t)(wv * 4) * 8192 + lane * 8;   // NS=16
  const u16* wp6 = W6p + (size_t)(wv * 2) * 8192 + lane * 8;

  const int rQ = row0 + m16;
  const float* ap = A0 + (size_t)(rQ < M ? rQ : (M - 1)) * 256 + quad * 8;

  // ---- layer 4: K=256, N=512; bx packed from f32 s1
  {
    floatx4 acc[4];
#pragma unroll
    for (int i = 0; i < 4; ++i) { floatx4 z = {0.f, 0.f, 0.f, 0.f}; acc[i] = z; }
#pragma unroll
    for (int s = 0; s < 8; ++s) {
      short8 af[4];
#pragma unroll
      for (int ni = 0; ni < 4; ++ni) af[ni] = *(const short8*)(wp4 + ni * 4096 + s * 512);
      short8 bx = pack8(*(const floatx4*)(ap + s * 32),
                        *(const floatx4*)(ap + s * 32 + 4));
#pragma unroll
      for (int ni = 0; ni < 4; ++ni)
        acc[ni] = __builtin_amdgcn_mfma_f32_16x16x32_bf16(af[ni], bx, acc[ni], 0, 0, 0);
    }
    const int n0 = wv * 64;
#pragma unroll
    for (int ni = 0; ni < 4; ++ni) {
      const int nb = n0 + ni * 16 + quad * 4;
      floatx4 bb = *(const floatx4*)&b4[nb];
      s4 h;
#pragma unroll
      for (int r = 0; r < 4; ++r) h[r] = bf16bits(lrelu(acc[ni][r] + bb[r]));
      *(s4*)&H[(size_t)m16 * NODE_NP + nb] = h;
    }
  }
  __syncthreads();

  // ---- layer 5: K=512, N=512; bx LDS, af prefetched
  {
    const u16* hp = H + (size_t)m16 * NODE_NP + quad * 8;
    floatx4 acc[4];
#pragma unroll
    for (int i = 0; i < 4; ++i) { floatx4 z = {0.f, 0.f, 0.f, 0.f}; acc[i] = z; }
    short8 af[4];
#pragma unroll
    for (int ni = 0; ni < 4; ++ni) af[ni] = *(const short8*)(wp5 + ni * 8192);
#pragma unroll 2
    for (int s = 0; s < 16; ++s) {
      short8 bx = *(const short8*)(hp + s * 32);
      short8 afn[4];
      const int sn = (s + 1) & 15;
#pragma unroll
      for (int ni = 0; ni < 4; ++ni) afn[ni] = *(const short8*)(wp5 + ni * 8192 + sn * 512);
#pragma unroll
      for (int ni = 0; ni < 4; ++ni)
        acc[ni] = __builtin_amdgcn_mfma_f32_16x16x32_bf16(af[ni], bx, acc[ni], 0, 0, 0);
#pragma unroll
      for (int ni = 0; ni < 4; ++ni) af[ni] = afn[ni];
    }
    __syncthreads();   // all waves done reading H4 before overwriting
    const int n0 = wv * 64;
#pragma unroll
    for (int ni = 0; ni < 4; ++ni) {
      const int nb = n0 + ni * 16 + quad * 4;
      floatx4 bb = *(const floatx4*)&b5[nb];
      s4 h;
#pragma unroll
      for (int r = 0; r < 4; ++r) h[r] = bf16bits(lrelu(acc[ni][r] + bb[r]));
      *(s4*)&H[(size_t)m16 * NODE_NP + nb] = h;
    }
  }
  __syncthreads();

  // ---- layer 6 + fused s2: K=512, N=256; mask-weighted reduce, no g3 store
  {
    const u16* hp = H + (size_t)m16 * NODE_NP + quad * 8;
    floatx4 acc[2];
#pragma unroll
    for (int i = 0; i < 2; ++i) { floatx4 z = {0.f, 0.f, 0.f, 0.f}; acc[i] = z; }
    short8 af[2];
#pragma unroll
    for (int ni = 0; ni < 2; ++ni) af[ni] = *(const short8*)(wp6 + ni * 8192);
#pragma unroll 2
    for (int s = 0; s < 16; ++s) {
      short8 bx = *(const short8*)(hp + s * 32);
      short8 afn[2];
      const int sn = (s + 1) & 15;
#pragma unroll
      for (int ni = 0; ni < 2; ++ni) afn[ni] = *(const short8*)(wp6 + ni * 8192 + sn * 512);
#pragma unroll
      for (int ni = 0; ni < 2; ++ni)
        acc[ni] = __builtin_amdgcn_mfma_f32_16x16x32_bf16(af[ni], bx, acc[ni], 0, 0, 0);
#pragma unroll
      for (int ni = 0; ni < 2; ++ni) af[ni] = afn[ni];
    }
    const int n0 = wv * 32;
    float sv[2][4];
#pragma unroll
    for (int ni = 0; ni < 2; ++ni)
#pragma unroll
      for (int r = 0; r < 4; ++r) sv[ni][r] = 0.f;
    {
      const int r0 = row0 + m16;
      if (r0 < M) {
        const float mk = mask[r0];
#pragma unroll
        for (int ni = 0; ni < 2; ++ni) {
          floatx4 bb = *(const floatx4*)&b6[n0 + ni * 16 + quad * 4];
#pragma unroll
          for (int r = 0; r < 4; ++r)
            sv[ni][r] += mk * lrelu(acc[ni][r] + bb[r]);
        }
      }
    }
#pragma unroll
    for (int j = 1; j < 16; j <<= 1)
#pragma unroll
      for (int ni = 0; ni < 2; ++ni)
#pragma unroll
        for (int r = 0; r < 4; ++r)
          sv[ni][r] += __shfl_xor(sv[ni][r], j);
    if (m16 == 0) {
#pragma unroll
      for (int ni = 0; ni < 2; ++ni)
#pragma unroll
        for (int r = 0; r < 4; ++r)
          atomicAdd(out + s2Off + n0 + ni * 16 + quad * 4 + r, sv[ni][r]);
    }
  }
}

extern "C" void kernel_launch(void* const* d_in, const int* in_sizes, int n_in,
                              void* d_out, int out_size, void* d_ws, size_t ws_size,
                              hipStream_t stream) {
  (void)in_sizes; (void)n_in; (void)ws_size;
  constexpr int N_    = 100000;
  constexpr int MPAD  = 100128;              // 2086 * 48
  constexpr int NTILE = MPAD / 48;           // 2086
  constexpr int NGRAN = MPAD / 16;           // 6258 Xp granules
  constexpr int IND   = 128;
  constexpr int H1D   = 512;
  constexpr int H2D   = 512;
  constexpr int OUTD  = 256;
  constexpr int NDAG  = 2000;

  const float* X    = (const float*)d_in[0];
  const int*   dag  = (const int*)d_in[1];
  const float* mask = (const float*)d_in[2];
  const float* W1 = (const float*)d_in[3];
  const float* b1 = (const float*)d_in[4];
  const float* W2 = (const float*)d_in[5];
  const float* b2 = (const float*)d_in[6];
  const float* W3 = (const float*)d_in[7];
  const float* b3 = (const float*)d_in[8];
  const float* W4 = (const float*)d_in[9];
  const float* b4 = (const float*)d_in[10];
  const float* W5 = (const float*)d_in[11];
  const float* b5 = (const float*)d_in[12];
  const float* W6 = (const float*)d_in[13];
  const float* b6 = (const float*)d_in[14];

  char* ws = (char*)d_ws;
  auto alloc = [&](size_t bytes) {
    char* p = ws;
    ws += (bytes + 255) & ~(size_t)255;
    return p;
  };
  u16* W1p = (u16*)alloc((size_t)H1D * IND * 2);    // packed fragment layouts
  u16* W2p = (u16*)alloc((size_t)H2D * H1D * 2);
  u16* W3p = (u16*)alloc((size_t)OUTD * H2D * 2);
  u16* W4p = (u16*)alloc((size_t)H1D * OUTD * 2);
  u16* W5p = (u16*)alloc((size_t)H2D * H1D * 2);
  u16* W6p = (u16*)alloc((size_t)OUTD * H2D * 2);
  int* hist    = (int*)alloc((size_t)NDAG * 4);     // 8000 -> slot 8192 B
  int* tilectr = (int*)alloc(256);                  // adjacent: one memset
  int* cursor  = (int*)alloc((size_t)NDAG * 4);
  int* perm    = (int*)alloc((size_t)N_ * 4);
  int* dsort   = (int*)alloc((size_t)(MPAD + 64) * 4);
  u16* Xp = (u16*)alloc((size_t)MPAD * IND * 2);    // packed fragment layout

  float* out = (float*)d_out;
  float* s1  = out;                // [2000][256] f32, output 0
  const int s2Off = NDAG * OUTD;

  hipFuncSetAttribute(reinterpret_cast<const void*>(&node_fused),
                      hipFuncAttributeMaxDynamicSharedMemorySize, NODE_LDS);
  hipFuncSetAttribute(reinterpret_cast<const void*>(&fused3g),
                      hipFuncAttributeMaxDynamicSharedMemorySize, G_LDS);

  // two memsets: outputs; hist+tilectr (contiguous ws slots)
  hipMemsetAsync(out, 0, (size_t)out_size * 4, stream);
  hipMemsetAsync(hist, 0, 8192 + 256, stream);

  // counting sort by dag id (scatter also writes the dsort -1 tail)
  hist_kernel<<<(N_ + 255) / 256, 256, 0, stream>>>(dag, hist, N_);
  scan_offsets<<<1, 256, 0, stream>>>(hist, cursor);
  scatter_kernel<<<(MPAD + 64 + 255) / 256, 256, 0, stream>>>(
      dag, cursor, perm, dsort, N_, MPAD + 64);

  // weight pack (blocks 0..767) + X gather/pack (blocks 768..), one launch
  prep_all<<<768 + NGRAN, 256, 0, stream>>>(W1, W2, W3, W4, W5, W6,
                                            W1p, W2p, W3p, W4p, W5p, W6p,
                                            X, perm, Xp, N_);

  // fused node stack: 768 blocks (3/CU) + dual prefetch (fits at VGPR<=85)
  node_fused<<<768, 512, NODE_LDS, stream>>>(Xp, W1p, W2p, W3p,
                                             b1, b2, b3, s1, dsort,
                                             tilectr, NTILE);

  // global stack, node-style, 16-row tiles: 125 blocks; s2 via atomics
  fused3g<<<(NDAG + G_ROWS - 1) / G_ROWS, 512, G_LDS, stream>>>(
      s1, W4p, W5p, W6p, b4, b5, b6, mask, out, s2Off, NDAG);
}

// Round 14
// 321.622 us; speedup vs baseline: 1.0314x; 1.0314x over previous
//
#include <hip/hip_runtime.h>
#include <hip/hip_bf16.h>

typedef unsigned short u16;
typedef __attribute__((ext_vector_type(8))) short short8;
typedef __attribute__((ext_vector_type(4))) short s4;
typedef __attribute__((ext_vector_type(4))) float floatx4;

__device__ __forceinline__ float lrelu(float x) { return x > 0.f ? x : 0.01f * x; }

__device__ __forceinline__ short bf16bits(float v) {
  __hip_bfloat16 t = __float2bfloat16(v);
  return *reinterpret_cast<short*>(&t);
}
__device__ __forceinline__ float bits2f(u16 b) {
  __hip_bfloat16 t = *reinterpret_cast<__hip_bfloat16*>(&b);
  return __bfloat162float(t);
}
__device__ __forceinline__ short8 pack8(floatx4 x0, floatx4 x1) {
  short8 b;
#pragma unroll
  for (int r = 0; r < 4; ++r) { b[r] = bf16bits(x0[r]); b[4 + r] = bf16bits(x1[r]); }
  return b;
}

// ---------------------------------------------------------------------------
// histpack: co-schedule the (perm-independent) weight fragment-pack with the
// dag histogram — the pack's ~10us hides under the hist pass (one less
// serial pass in the chain).
//   blocks [0, 768): fragment-pack six weights (z = bid>>7, 128 blocks each)
//   blocks [768, ...): histogram of dag ids (2000 bins, atomics)
// Pack layout: W[K][N] f32 -> P[(g*NS+s)*512 + lane*8 + j] bf16,
// g = col-group (16 cols), s = k-step (32 k), lane = quad*16+m16:
//   P[...] = W[s*32 + quad*8 + j][g*16 + m16]
// Wave af fragment load = 64 lanes x 16B CONTIGUOUS (8 cache lines).
// ---------------------------------------------------------------------------
__global__ __launch_bounds__(256) void histpack(
    const float* __restrict__ W1, const float* __restrict__ W2,
    const float* __restrict__ W3, const float* __restrict__ W4,
    const float* __restrict__ W5, const float* __restrict__ W6,
    u16* __restrict__ P1, u16* __restrict__ P2, u16* __restrict__ P3,
    u16* __restrict__ P4, u16* __restrict__ P5, u16* __restrict__ P6,
    const int* __restrict__ dag, int* __restrict__ hist, int n) {
  const int bid = blockIdx.x;
  if (bid < 768) {
    const float* W; u16* P; int N, ls, total;
    switch (bid >> 7) {
      case 0: W = W1; P = P1; N = 512; ls = 2; total = 8192;  break;  // K=128
      case 1: W = W2; P = P2; N = 512; ls = 4; total = 32768; break;  // K=512
      case 2: W = W3; P = P3; N = 256; ls = 4; total = 16384; break;  // K=512
      case 3: W = W4; P = P4; N = 512; ls = 3; total = 16384; break;  // K=256
      case 4: W = W5; P = P5; N = 512; ls = 4; total = 32768; break;  // K=512
      default: W = W6; P = P6; N = 256; ls = 4; total = 16384; break; // K=512
    }
    const int t = (bid & 127) * 256 + threadIdx.x;
    if (t >= total) return;
    const int lane = t & 63;
    const int sg   = t >> 6;
    const int m16  = lane & 15;
    const int quad = lane >> 4;
    const int s    = sg & ((1 << ls) - 1);
    const int g    = sg >> ls;
    const int nn   = g * 16 + m16;
    const int k0   = s * 32 + quad * 8;
    short8 out;
#pragma unroll
    for (int j = 0; j < 8; ++j) out[j] = bf16bits(W[(size_t)(k0 + j) * N + nn]);
    *(short8*)(P + (size_t)t * 8) = out;
  } else {
    const int i = (bid - 768) * 256 + threadIdx.x;
    if (i < n) atomicAdd(&hist[dag[i]], 1);
  }
}

__global__ __launch_bounds__(256) void scan_offsets(const int* __restrict__ hist,
                                                    int* __restrict__ cursor) {
  __shared__ int part[256];
  const int t = threadIdx.x;
  const int base = t * 8;
  int loc[8];
  int s = 0;
#pragma unroll
  for (int j = 0; j < 8; ++j) {
    int v = (base + j < 2000) ? hist[base + j] : 0;
    loc[j] = s;
    s += v;
  }
  part[t] = s;
  __syncthreads();
  int val = s;
  for (int off = 1; off < 256; off <<= 1) {
    int tmp = (t >= off) ? part[t - off] : 0;
    __syncthreads();
    val += tmp;
    part[t] = val;
    __syncthreads();
  }
  const int chunkBase = (t == 0) ? 0 : part[t - 1];
#pragma unroll
  for (int j = 0; j < 8; ++j)
    if (base + j < 2000) cursor[base + j] = chunkBase + loc[j];
}

// scatter + dsort tail fill in one launch (tail threads write -1 pad).
__global__ __launch_bounds__(256) void scatter_kernel(const int* __restrict__ dag,
                                                      int* __restrict__ cursor,
                                                      int* __restrict__ perm,
                                                      int* __restrict__ dsort,
                                                      int n, int nTot) {
  int i = blockIdx.x * blockDim.x + threadIdx.x;
  if (i < n) {
    int d = dag[i];
    int p = atomicAdd(&cursor[d], 1);
    perm[p] = i;
    dsort[p] = d;
  } else if (i < nTot) {
    dsort[i] = -1;
  }
}

// ---------------------------------------------------------------------------
// Gather X rows into sorted order + fragment-pack (16-row granules):
// Xp[(tg*4+s)*512 + lane*8 + j] = bf16(X[perm[tg*16+m16]][s*32+quad*8+j]);
// pad rows (>= n) write zeros. Standalone full-TLP stream (r9 lesson).
// ---------------------------------------------------------------------------
__global__ __launch_bounds__(256) void xp_conv(const float* __restrict__ X,
                                               const int* __restrict__ perm,
                                               u16* __restrict__ Xp, int n) {
  const int t = blockIdx.x * 256 + threadIdx.x;    // (tg*4 + s)*64 + lane
  const int lane = t & 63;
  const int s    = (t >> 6) & 3;
  const int tg   = t >> 8;
  const int m16  = lane & 15;
  const int quad = lane >> 4;
  const int R    = tg * 16 + m16;
  short8 out = {0, 0, 0, 0, 0, 0, 0, 0};
  if (R < n) {
    const int src = perm[R];
    const float* xp = X + (size_t)src * 128 + s * 32 + quad * 8;
    out = pack8(*(const floatx4*)xp, *(const floatx4*)(xp + 4));
  }
  *(short8*)(Xp + (size_t)t * 8) = out;
}

// ---------------------------------------------------------------------------
// Fused node stack — EXACT r11 measured body (155.4 us, VGPR 76, FETCH
// 16.5MB): launch_bounds(512,2) (cap 128), grid 512 = 2 blocks/CU,
// work-stealing, 48-row tiles, DUAL PREFETCH in the L2/L3 k-loops.
// r12 lesson: 3 blocks/CU + dual-pf do NOT compose (163.5us; occupancy
// counter identical) — they cover the same stall window. Keep r11 config.
//   L1: H1 = lrelu(Xp@W1+b1)  K=128   af+bx packed-global (16B/lane coalesced)
//   L2: H2 = lrelu(H1@W2+b2)  K=512   bx LDS + af global, BOTH prefetched
//   L3: G  = lrelu(H2@W3+b3)  K=512   same; -> LDS, dag-sum -> atomics s1
// mfma(af, bx, acc): out row = bx-row (mi*16+m16), col = af-row (ni*16+quad*4+r).
// ---------------------------------------------------------------------------
#define NODE_ROWS 48
#define NODE_NP 520
#define NODE_P3 264
#define NODE_LDS (NODE_ROWS * NODE_NP * 2 + 16)   // 49936 B

__global__ __launch_bounds__(512, 2) void node_fused(
    const u16* __restrict__ Xp, const u16* __restrict__ W1p,
    const u16* __restrict__ W2p, const u16* __restrict__ W3p,
    const float* __restrict__ b1, const float* __restrict__ b2,
    const float* __restrict__ b3, float* __restrict__ s1,
    const int* __restrict__ dsort, int* __restrict__ tilectr, int nTiles) {
  extern __shared__ __align__(16) char lds[];
  u16* H = (u16*)lds;   // [48][520] for H1/H2, reused as [48][264] for L3
  int* tileSlot = (int*)(lds + NODE_ROWS * NODE_NP * 2);

  const int tid  = threadIdx.x;
  const int wv   = tid >> 6;
  const int lane = tid & 63;
  const int m16  = lane & 15;
  const int quad = lane >> 4;

  // loop-invariant fragment base pointers (chunk = 512 u16 per (g,s))
  const u16* wp1 = W1p + (size_t)(wv * 4) * 2048 + lane * 8;   // g-stride 4*512
  const u16* wp2 = W2p + (size_t)(wv * 4) * 8192 + lane * 8;   // g-stride 16*512
  const u16* wp3 = W3p + (size_t)(wv * 2) * 8192 + lane * 8;

  for (;;) {
    if (tid == 0) *tileSlot = atomicAdd(tilectr, 1);
    __syncthreads();                      // also: all waves done with prev walk
    const int tile = *tileSlot;
    if (tile >= nTiles) return;           // uniform exit

    // ---- layer 1: K=128, N=512; bx from packed global Xp (4 steps, no pf)
    {
      const u16* xpp = Xp + (size_t)tile * 12 * 512 + lane * 8;
      floatx4 acc[4][3];
#pragma unroll
      for (int i = 0; i < 4; ++i)
#pragma unroll
        for (int j = 0; j < 3; ++j) { floatx4 z = {0.f, 0.f, 0.f, 0.f}; acc[i][j] = z; }
#pragma unroll
      for (int s = 0; s < 4; ++s) {
        short8 af[4], bx[3];
#pragma unroll
        for (int ni = 0; ni < 4; ++ni) af[ni] = *(const short8*)(wp1 + ni * 2048 + s * 512);
#pragma unroll
        for (int mi = 0; mi < 3; ++mi) bx[mi] = *(const short8*)(xpp + (mi * 4 + s) * 512);
#pragma unroll
        for (int ni = 0; ni < 4; ++ni)
#pragma unroll
          for (int mi = 0; mi < 3; ++mi)
            acc[ni][mi] = __builtin_amdgcn_mfma_f32_16x16x32_bf16(af[ni], bx[mi], acc[ni][mi], 0, 0, 0);
      }
      const int n0 = wv * 64;
#pragma unroll
      for (int ni = 0; ni < 4; ++ni) {
        const int nb = n0 + ni * 16 + quad * 4;
        floatx4 bb = *(const floatx4*)&b1[nb];
#pragma unroll
        for (int mi = 0; mi < 3; ++mi) {
          s4 h;
#pragma unroll
          for (int r = 0; r < 4; ++r) h[r] = bf16bits(lrelu(acc[ni][mi][r] + bb[r]));
          *(s4*)&H[(size_t)(mi * 16 + m16) * NODE_NP + nb] = h;
        }
      }
    }
    __syncthreads();

    // ---- layer 2: K=512, N=512; DUAL prefetch (af global + bx LDS)
    {
      const u16* hp = H + (size_t)m16 * NODE_NP + quad * 8;
      floatx4 acc[4][3];
#pragma unroll
      for (int i = 0; i < 4; ++i)
#pragma unroll
        for (int j = 0; j < 3; ++j) { floatx4 z = {0.f, 0.f, 0.f, 0.f}; acc[i][j] = z; }
      short8 af[4], bx[3];
#pragma unroll
      for (int ni = 0; ni < 4; ++ni) af[ni] = *(const short8*)(wp2 + ni * 8192);
#pragma unroll
      for (int mi = 0; mi < 3; ++mi) bx[mi] = *(const short8*)(hp + mi * (16 * NODE_NP));
#pragma unroll 2
      for (int s = 0; s < 16; ++s) {
        const int sn = (s + 1) & 15;   // s=15 wraps: dead reload, branchless
        short8 afn[4], bxn[3];
#pragma unroll
        for (int ni = 0; ni < 4; ++ni) afn[ni] = *(const short8*)(wp2 + ni * 8192 + sn * 512);
#pragma unroll
        for (int mi = 0; mi < 3; ++mi)
          bxn[mi] = *(const short8*)(hp + mi * (16 * NODE_NP) + sn * 32);
#pragma unroll
        for (int ni = 0; ni < 4; ++ni)
#pragma unroll
          for (int mi = 0; mi < 3; ++mi)
            acc[ni][mi] = __builtin_amdgcn_mfma_f32_16x16x32_bf16(af[ni], bx[mi], acc[ni][mi], 0, 0, 0);
#pragma unroll
        for (int ni = 0; ni < 4; ++ni) af[ni] = afn[ni];
#pragma unroll
        for (int mi = 0; mi < 3; ++mi) bx[mi] = bxn[mi];
      }
      __syncthreads();   // all waves done reading H1 before overwriting
      const int n0 = wv * 64;
#pragma unroll
      for (int ni = 0; ni < 4; ++ni) {
        const int nb = n0 + ni * 16 + quad * 4;
        floatx4 bb = *(const floatx4*)&b2[nb];
#pragma unroll
        for (int mi = 0; mi < 3; ++mi) {
          s4 h;
#pragma unroll
          for (int r = 0; r < 4; ++r) h[r] = bf16bits(lrelu(acc[ni][mi][r] + bb[r]));
          *(s4*)&H[(size_t)(mi * 16 + m16) * NODE_NP + nb] = h;
        }
      }
    }
    __syncthreads();

    // ---- layer 3: K=512, N=256; DUAL prefetch; wave cols [wv*32, wv*32+32)
    {
      const u16* hp = H + (size_t)m16 * NODE_NP + quad * 8;
      floatx4 acc[2][3];
#pragma unroll
      for (int i = 0; i < 2; ++i)
#pragma unroll
        for (int j = 0; j < 3; ++j) { floatx4 z = {0.f, 0.f, 0.f, 0.f}; acc[i][j] = z; }
      short8 af[2], bx[3];
#pragma unroll
      for (int ni = 0; ni < 2; ++ni) af[ni] = *(const short8*)(wp3 + ni * 8192);
#pragma unroll
      for (int mi = 0; mi < 3; ++mi) bx[mi] = *(const short8*)(hp + mi * (16 * NODE_NP));
#pragma unroll 2
      for (int s = 0; s < 16; ++s) {
        const int sn = (s + 1) & 15;
        short8 afn[2], bxn[3];
#pragma unroll
        for (int ni = 0; ni < 2; ++ni) afn[ni] = *(const short8*)(wp3 + ni * 8192 + sn * 512);
#pragma unroll
        for (int mi = 0; mi < 3; ++mi)
          bxn[mi] = *(const short8*)(hp + mi * (16 * NODE_NP) + sn * 32);
#pragma unroll
        for (int ni = 0; ni < 2; ++ni)
#pragma unroll
          for (int mi = 0; mi < 3; ++mi)
            acc[ni][mi] = __builtin_amdgcn_mfma_f32_16x16x32_bf16(af[ni], bx[mi], acc[ni][mi], 0, 0, 0);
#pragma unroll
        for (int ni = 0; ni < 2; ++ni) af[ni] = afn[ni];
#pragma unroll
        for (int mi = 0; mi < 3; ++mi) bx[mi] = bxn[mi];
      }
      __syncthreads();   // all waves done reading H2
      const int n0 = wv * 32;
#pragma unroll
      for (int ni = 0; ni < 2; ++ni) {
        const int nb = n0 + ni * 16 + quad * 4;
        floatx4 bb = *(const floatx4*)&b3[nb];
#pragma unroll
        for (int mi = 0; mi < 3; ++mi) {
          s4 h;
#pragma unroll
          for (int r = 0; r < 4; ++r) h[r] = bf16bits(lrelu(acc[ni][mi][r] + bb[r]));
          *(s4*)&H[(size_t)(mi * 16 + m16) * NODE_P3 + nb] = h;
        }
      }
    }
    __syncthreads();

    // ---- segmented dag walk: wave wv owns rows [(wv>>2)*24, +24), cols
    // [(wv&3)*64, +64); lane = local col. dsort sorted; -1 (pad) skipped.
    {
      const int rh = (wv >> 2) * 24;
      const int c0 = (wv & 3) * 64;
      const int myDag = dsort[(size_t)tile * NODE_ROWS + rh + (lane & 31)];
      float* so = s1 + c0 + lane;
      float run = 0.f;
      int cur = __shfl(myDag, 0);
#pragma unroll
      for (int rb = 0; rb < 24; rb += 8) {
        float v[8];
#pragma unroll
        for (int j = 0; j < 8; ++j)
          v[j] = bits2f(H[(size_t)(rh + rb + j) * NODE_P3 + c0 + lane]);
#pragma unroll
        for (int j = 0; j < 8; ++j) {
          int d = __shfl(myDag, rb + j);              // wave-uniform
          if (d != cur) {
            if (cur >= 0) atomicAdd(so + (size_t)cur * 256, run);
            run = 0.f; cur = d;
          }
          run += v[j];
        }
      }
      if (cur >= 0) atomicAdd(so + (size_t)cur * 256, run);
    }
  }
}

// ---------------------------------------------------------------------------
// Global stack, node-style, 16-row tiles: 125 blocks (2000 = 125x16).
//   L4: H = lrelu(s1@W4+b4)  K=256  bx packed on the fly from f32 s1
//   L5: H = lrelu(H@W5+b5)   K=512  bx LDS, af packed-global prefetched
//   L6: g3 = lrelu(H@W6+b6)  K=512  mask-weighted row-reduce -> atomics s2
// ---------------------------------------------------------------------------
#define G_ROWS 16
#define G_LDS (G_ROWS * NODE_NP * 2)   // 16640 B

__global__ __launch_bounds__(512, 3) void fused3g(
    const float* __restrict__ A0, const u16* __restrict__ W4p,
    const u16* __restrict__ W5p, const u16* __restrict__ W6p,
    const float* __restrict__ b4, const float* __restrict__ b5,
    const float* __restrict__ b6, const float* __restrict__ mask,
    float* __restrict__ out, int s2Off, int M) {
  extern __shared__ __align__(16) char lds[];
  u16* H = (u16*)lds;   // [16][520]

  const int tid  = threadIdx.x;
  const int wv   = tid >> 6;
  const int lane = tid & 63;
  const int m16  = lane & 15;
  const int quad = lane >> 4;
  const int row0 = blockIdx.x * G_ROWS;

  const u16* wp4 = W4p + (size_t)(wv * 4) * 4096 + lane * 8;   // NS=8
  const u16* wp5 = W5p + (size_t)(wv * 4) * 8192 + lane * 8;   // NS=16
  const u16* wp6 = W6p + (size_t)(wv * 2) * 8192 + lane * 8;

  const int rQ = row0 + m16;
  const float* ap = A0 + (size_t)(rQ < M ? rQ : (M - 1)) * 256 + quad * 8;

  // ---- layer 4: K=256, N=512; bx packed from f32 s1
  {
    floatx4 acc[4];
#pragma unroll
    for (int i = 0; i < 4; ++i) { floatx4 z = {0.f, 0.f, 0.f, 0.f}; acc[i] = z; }
#pragma unroll
    for (int s = 0; s < 8; ++s) {
      short8 af[4];
#pragma unroll
      for (int ni = 0; ni < 4; ++ni) af[ni] = *(const short8*)(wp4 + ni * 4096 + s * 512);
      short8 bx = pack8(*(const floatx4*)(ap + s * 32),
                        *(const floatx4*)(ap + s * 32 + 4));
#pragma unroll
      for (int ni = 0; ni < 4; ++ni)
        acc[ni] = __builtin_amdgcn_mfma_f32_16x16x32_bf16(af[ni], bx, acc[ni], 0, 0, 0);
    }
    const int n0 = wv * 64;
#pragma unroll
    for (int ni = 0; ni < 4; ++ni) {
      const int nb = n0 + ni * 16 + quad * 4;
      floatx4 bb = *(const floatx4*)&b4[nb];
      s4 h;
#pragma unroll
      for (int r = 0; r < 4; ++r) h[r] = bf16bits(lrelu(acc[ni][r] + bb[r]));
      *(s4*)&H[(size_t)m16 * NODE_NP + nb] = h;
    }
  }
  __syncthreads();

  // ---- layer 5: K=512, N=512; bx LDS, af prefetched
  {
    const u16* hp = H + (size_t)m16 * NODE_NP + quad * 8;
    floatx4 acc[4];
#pragma unroll
    for (int i = 0; i < 4; ++i) { floatx4 z = {0.f, 0.f, 0.f, 0.f}; acc[i] = z; }
    short8 af[4];
#pragma unroll
    for (int ni = 0; ni < 4; ++ni) af[ni] = *(const short8*)(wp5 + ni * 8192);
#pragma unroll 2
    for (int s = 0; s < 16; ++s) {
      short8 bx = *(const short8*)(hp + s * 32);
      short8 afn[4];
      const int sn = (s + 1) & 15;
#pragma unroll
      for (int ni = 0; ni < 4; ++ni) afn[ni] = *(const short8*)(wp5 + ni * 8192 + sn * 512);
#pragma unroll
      for (int ni = 0; ni < 4; ++ni)
        acc[ni] = __builtin_amdgcn_mfma_f32_16x16x32_bf16(af[ni], bx, acc[ni], 0, 0, 0);
#pragma unroll
      for (int ni = 0; ni < 4; ++ni) af[ni] = afn[ni];
    }
    __syncthreads();   // all waves done reading H4 before overwriting
    const int n0 = wv * 64;
#pragma unroll
    for (int ni = 0; ni < 4; ++ni) {
      const int nb = n0 + ni * 16 + quad * 4;
      floatx4 bb = *(const floatx4*)&b5[nb];
      s4 h;
#pragma unroll
      for (int r = 0; r < 4; ++r) h[r] = bf16bits(lrelu(acc[ni][r] + bb[r]));
      *(s4*)&H[(size_t)m16 * NODE_NP + nb] = h;
    }
  }
  __syncthreads();

  // ---- layer 6 + fused s2: K=512, N=256; mask-weighted reduce, no g3 store
  {
    const u16* hp = H + (size_t)m16 * NODE_NP + quad * 8;
    floatx4 acc[2];
#pragma unroll
    for (int i = 0; i < 2; ++i) { floatx4 z = {0.f, 0.f, 0.f, 0.f}; acc[i] = z; }
    short8 af[2];
#pragma unroll
    for (int ni = 0; ni < 2; ++ni) af[ni] = *(const short8*)(wp6 + ni * 8192);
#pragma unroll 2
    for (int s = 0; s < 16; ++s) {
      short8 bx = *(const short8*)(hp + s * 32);
      short8 afn[2];
      const int sn = (s + 1) & 15;
#pragma unroll
      for (int ni = 0; ni < 2; ++ni) afn[ni] = *(const short8*)(wp6 + ni * 8192 + sn * 512);
#pragma unroll
      for (int ni = 0; ni < 2; ++ni)
        acc[ni] = __builtin_amdgcn_mfma_f32_16x16x32_bf16(af[ni], bx, acc[ni], 0, 0, 0);
#pragma unroll
      for (int ni = 0; ni < 2; ++ni) af[ni] = afn[ni];
    }
    const int n0 = wv * 32;
    float sv[2][4];
#pragma unroll
    for (int ni = 0; ni < 2; ++ni)
#pragma unroll
      for (int r = 0; r < 4; ++r) sv[ni][r] = 0.f;
    {
      const int r0 = row0 + m16;
      if (r0 < M) {
        const float mk = mask[r0];
#pragma unroll
        for (int ni = 0; ni < 2; ++ni) {
          floatx4 bb = *(const floatx4*)&b6[n0 + ni * 16 + quad * 4];
#pragma unroll
          for (int r = 0; r < 4; ++r)
            sv[ni][r] += mk * lrelu(acc[ni][r] + bb[r]);
        }
      }
    }
#pragma unroll
    for (int j = 1; j < 16; j <<= 1)
#pragma unroll
      for (int ni = 0; ni < 2; ++ni)
#pragma unroll
        for (int r = 0; r < 4; ++r)
          sv[ni][r] += __shfl_xor(sv[ni][r], j);
    if (m16 == 0) {
#pragma unroll
      for (int ni = 0; ni < 2; ++ni)
#pragma unroll
        for (int r = 0; r < 4; ++r)
          atomicAdd(out + s2Off + n0 + ni * 16 + quad * 4 + r, sv[ni][r]);
    }
  }
}

extern "C" void kernel_launch(void* const* d_in, const int* in_sizes, int n_in,
                              void* d_out, int out_size, void* d_ws, size_t ws_size,
                              hipStream_t stream) {
  (void)in_sizes; (void)n_in; (void)ws_size;
  constexpr int N_    = 100000;
  constexpr int MPAD  = 100128;              // 2086 * 48
  constexpr int NTILE = MPAD / 48;           // 2086
  constexpr int NGRAN = MPAD / 16;           // 6258 Xp granules
  constexpr int IND   = 128;
  constexpr int H1D   = 512;
  constexpr int H2D   = 512;
  constexpr int OUTD  = 256;
  constexpr int NDAG  = 2000;

  const float* X    = (const float*)d_in[0];
  const int*   dag  = (const int*)d_in[1];
  const float* mask = (const float*)d_in[2];
  const float* W1 = (const float*)d_in[3];
  const float* b1 = (const float*)d_in[4];
  const float* W2 = (const float*)d_in[5];
  const float* b2 = (const float*)d_in[6];
  const float* W3 = (const float*)d_in[7];
  const float* b3 = (const float*)d_in[8];
  const float* W4 = (const float*)d_in[9];
  const float* b4 = (const float*)d_in[10];
  const float* W5 = (const float*)d_in[11];
  const float* b5 = (const float*)d_in[12];
  const float* W6 = (const float*)d_in[13];
  const float* b6 = (const float*)d_in[14];

  char* ws = (char*)d_ws;
  auto alloc = [&](size_t bytes) {
    char* p = ws;
    ws += (bytes + 255) & ~(size_t)255;
    return p;
  };
  u16* W1p = (u16*)alloc((size_t)H1D * IND * 2);    // packed fragment layouts
  u16* W2p = (u16*)alloc((size_t)H2D * H1D * 2);
  u16* W3p = (u16*)alloc((size_t)OUTD * H2D * 2);
  u16* W4p = (u16*)alloc((size_t)H1D * OUTD * 2);
  u16* W5p = (u16*)alloc((size_t)H2D * H1D * 2);
  u16* W6p = (u16*)alloc((size_t)OUTD * H2D * 2);
  int* hist    = (int*)alloc((size_t)NDAG * 4);     // 8000 -> slot 8192 B
  int* tilectr = (int*)alloc(256);                  // adjacent: one memset
  int* cursor  = (int*)alloc((size_t)NDAG * 4);
  int* perm    = (int*)alloc((size_t)N_ * 4);
  int* dsort   = (int*)alloc((size_t)(MPAD + 64) * 4);
  u16* Xp = (u16*)alloc((size_t)MPAD * IND * 2);    // packed fragment layout

  float* out = (float*)d_out;
  float* s1  = out;                // [2000][256] f32, output 0
  const int s2Off = NDAG * OUTD;

  hipFuncSetAttribute(reinterpret_cast<const void*>(&node_fused),
                      hipFuncAttributeMaxDynamicSharedMemorySize, NODE_LDS);
  hipFuncSetAttribute(reinterpret_cast<const void*>(&fused3g),
                      hipFuncAttributeMaxDynamicSharedMemorySize, G_LDS);

  // two memsets: outputs; hist+tilectr (contiguous ws slots)
  hipMemsetAsync(out, 0, (size_t)out_size * 4, stream);
  hipMemsetAsync(hist, 0, 8192 + 256, stream);

  // weight pack (blocks 0..767) co-scheduled with dag histogram (768..)
  histpack<<<768 + (N_ + 255) / 256, 256, 0, stream>>>(
      W1, W2, W3, W4, W5, W6, W1p, W2p, W3p, W4p, W5p, W6p, dag, hist, N_);

  scan_offsets<<<1, 256, 0, stream>>>(hist, cursor);
  scatter_kernel<<<(MPAD + 64 + 255) / 256, 256, 0, stream>>>(
      dag, cursor, perm, dsort, N_, MPAD + 64);

  // gather + fragment-pack X (standalone full-TLP stream)
  xp_conv<<<NGRAN, 256, 0, stream>>>(X, perm, Xp, N_);

  // fused node stack: r11 config — 512 blocks (2/CU), dual prefetch
  node_fused<<<512, 512, NODE_LDS, stream>>>(Xp, W1p, W2p, W3p,
                                             b1, b2, b3, s1, dsort,
                                             tilectr, NTILE);

  // global stack, node-style, 16-row tiles: 125 blocks; s2 via atomics
  fused3g<<<(NDAG + G_ROWS - 1) / G_ROWS, 512, G_LDS, stream>>>(
      s1, W4p, W5p, W6p, b4, b5, b6, mask, out, s2Off, NDAG);
}